// Round 8
// baseline (69.961 us; speedup 1.0000x reference)
//
#include <hip/hip_runtime.h>
#include <hip/hip_bf16.h>

#define N_ 4096
#define D_ 768
#define NCLS 128
#define BM 256
#define BN 256
#define BK 64
#define NSTEP 12  // D_/BK

typedef __bf16 bf16x8 __attribute__((ext_vector_type(8)));
typedef float f32x4 __attribute__((ext_vector_type(4)));
typedef short s16x8 __attribute__((ext_vector_type(8)));

// Normalize both embedding matrices (blocks [0,N) -> img, [N,2N) -> txt).
__global__ __launch_bounds__(192) void normalize_kernel(
    const float* __restrict__ img, const float* __restrict__ txt,
    __hip_bfloat16* __restrict__ img_nb, __hip_bfloat16* __restrict__ txt_nb) {
  int b = blockIdx.x;
  const float* s;
  __hip_bfloat16* d;
  if (b < N_) {
    s = img + (size_t)b * D_;
    d = img_nb + (size_t)b * D_;
  } else {
    s = txt + (size_t)(b - N_) * D_;
    d = txt_nb + (size_t)(b - N_) * D_;
  }
  int tid = threadIdx.x;
  float4 v = ((const float4*)s)[tid];
  float ss = v.x * v.x + v.y * v.y + v.z * v.z + v.w * v.w;
#pragma unroll
  for (int m = 32; m; m >>= 1) ss += __shfl_xor(ss, m);
  __shared__ float wsum[3];
  int lane = tid & 63, w = tid >> 6;
  if (lane == 0) wsum[w] = ss;
  __syncthreads();
  float inv = 1.0f / fmaxf(sqrtf(wsum[0] + wsum[1] + wsum[2]), 1e-8f);
  ushort4 o;
  o.x = __bfloat16_as_ushort(__float2bfloat16(v.x * inv));
  o.y = __bfloat16_as_ushort(__float2bfloat16(v.y * inv));
  o.z = __bfloat16_as_ushort(__float2bfloat16(v.z * inv));
  o.w = __bfloat16_as_ushort(__float2bfloat16(v.w * inv));
  ((ushort4*)d)[tid] = o;
}

// 256x256-tile GEMM, 512 thr / 8 waves (2x4), per-wave 128x64 output
// (acc[8][4] f32x4, all-static indexing). r7's proven staging: coalesced VGPR
// loads (8 lanes cover one row's 128B), XOR-swizzled LDS pos(row,g)=row*8+(g^(row&7))
// conflict-free both sides. Explicit reg prefetch of step u+1 between ds_write(u)
// and the compute barrier. 64 MFMA per barrier pair per wave.
__global__ __launch_bounds__(512) void gemm_epi_kernel(
    const unsigned short* __restrict__ A, const unsigned short* __restrict__ B,
    const int* __restrict__ labels, float* __restrict__ row_part,
    float* __restrict__ col_part, float* __restrict__ S_part) {
  __shared__ __align__(16) unsigned short As[16384];  // 256 rows x 8 chunks x 8 elems
  __shared__ __align__(16) unsigned short Bs[16384];
  __shared__ int labR[BM], labC[BN];
  __shared__ float rbuf[4][BM], cbuf[2][BN];
  __shared__ float sbuf[8];

  const int bx = blockIdx.x, by = blockIdx.y;
  const int tid = threadIdx.x;
  const int lane = tid & 63, wave = tid >> 6;
  const int wr = wave >> 2, wc = wave & 3;  // 2x4 wave grid; wave owns 128x64
  const int g = lane >> 4, fr = lane & 15;
  const int rowBase = by * BM, colBase = bx * BN;

  if (tid < BM) labR[tid] = labels[rowBase + tid];
  else labC[tid - BM] = labels[colBase + tid - BM];

  // staging: thread t covers chunk col gq=t&7, rows rbase+64j (j=0..3)
  const int gq = tid & 7, rbase = tid >> 3;  // rbase 0..63
  const unsigned short* pa = A + (size_t)(rowBase + rbase) * D_ + gq * 8;
  const unsigned short* pb = B + (size_t)(colBase + rbase) * D_ + gq * 8;
  const int wpos = (rbase * 8 + (gq ^ (rbase & 7))) * 8;  // +j*4096 for rows +64j

  f32x4 acc[8][4] = {};

  // prologue: step 0 into regs
  s16x8 ra[4], rb[4];
#pragma unroll
  for (int j = 0; j < 4; ++j) {
    ra[j] = *(const s16x8*)(pa + (size_t)(64 * j) * D_);
    rb[j] = *(const s16x8*)(pb + (size_t)(64 * j) * D_);
  }

  for (int u = 0; u < NSTEP; ++u) {
    __syncthreads();  // all waves done reading LDS from previous step
#pragma unroll
    for (int j = 0; j < 4; ++j) {
      *(s16x8*)&As[wpos + j * 4096] = ra[j];
      *(s16x8*)&Bs[wpos + j * 4096] = rb[j];
    }
    if (u + 1 < NSTEP) {  // prefetch next step into regs; lands during MFMA below
      const int k0 = (u + 1) * BK;
#pragma unroll
      for (int j = 0; j < 4; ++j) {
        ra[j] = *(const s16x8*)(pa + (size_t)(64 * j) * D_ + k0);
        rb[j] = *(const s16x8*)(pb + (size_t)(64 * j) * D_ + k0);
      }
    }
    __syncthreads();  // tile u resident
#pragma unroll
    for (int ks = 0; ks < 2; ++ks) {
      const int sw = (ks * 4 + g) ^ (fr & 7);  // chunk col, swizzled; row&7 == fr&7
      bf16x8 bf[4];
#pragma unroll
      for (int n = 0; n < 4; ++n)
        bf[n] = *(const bf16x8*)&Bs[((wc * 64 + n * 16 + fr) * 8 + sw) * 8];
#pragma unroll
      for (int m = 0; m < 8; ++m) {
        bf16x8 af = *(const bf16x8*)&As[((wr * 128 + m * 16 + fr) * 8 + sw) * 8];
#pragma unroll
        for (int n = 0; n < 4; ++n)
          acc[m][n] = __builtin_amdgcn_mfma_f32_16x16x32_bf16(af, bf[n], acc[m][n], 0, 0, 0);
      }
    }
  }
  __syncthreads();

  const float scale = 14.285714285714286f;  // 1/0.07
  float sPart = 0.f;
  float colAcc[4] = {0.f, 0.f, 0.f, 0.f};
#pragma unroll
  for (int m = 0; m < 8; ++m) {
    float ra2[4] = {0.f, 0.f, 0.f, 0.f};
#pragma unroll
    for (int n = 0; n < 4; ++n) {
      int col = wc * 64 + n * 16 + fr;
      int lc = labC[col];
#pragma unroll
      for (int r = 0; r < 4; ++r) {
        float v = acc[m][n][r] * scale;
        float e = __expf(v);
        ra2[r] += e;
        colAcc[n] += e;
        int row = wr * 128 + m * 16 + g * 4 + r;
        if (labR[row] == lc) sPart += v;
      }
    }
#pragma unroll
    for (int r = 0; r < 4; ++r) {
      float x = ra2[r];
      x += __shfl_xor(x, 1);
      x += __shfl_xor(x, 2);
      x += __shfl_xor(x, 4);
      x += __shfl_xor(x, 8);
      if (fr == 0) rbuf[wc][wr * 128 + m * 16 + g * 4 + r] = x;
    }
  }
#pragma unroll
  for (int n = 0; n < 4; ++n) {
    float x = colAcc[n];
    x += __shfl_xor(x, 16);
    x += __shfl_xor(x, 32);
    if (g == 0 && lane < 16) cbuf[wr][wc * 64 + n * 16 + fr] = x;
  }
  float s = sPart;
#pragma unroll
  for (int m = 32; m; m >>= 1) s += __shfl_xor(s, m);
  if (lane == 0) sbuf[wave] = s;
  __syncthreads();
  if (tid < BM) {
    row_part[(size_t)bx * N_ + rowBase + tid] =
        rbuf[0][tid] + rbuf[1][tid] + rbuf[2][tid] + rbuf[3][tid];
  } else {
    int c = tid - BM;
    col_part[(size_t)by * N_ + colBase + c] = cbuf[0][c] + cbuf[1][c];
  }
  if (tid == 0)
    S_part[by * 16 + bx] =
        sbuf[0] + sbuf[1] + sbuf[2] + sbuf[3] + sbuf[4] + sbuf[5] + sbuf[6] + sbuf[7];
}

// Per-block local histogram; partials out (no atomics, no memset needed)
__global__ __launch_bounds__(256) void reduce_kernel(
    const float* __restrict__ row_part, const float* __restrict__ col_part,
    const float* __restrict__ S_part, const int* __restrict__ labels,
    double* __restrict__ partials) {
  __shared__ int hist[NCLS];
  int tid = threadIdx.x;
  if (tid < NCLS) hist[tid] = 0;
  __syncthreads();
  for (int j = tid; j < N_; j += 256) atomicAdd(&hist[labels[j]], 1);
  __syncthreads();

  int i = blockIdx.x * 256 + tid;  // 0..4095
  float rs = 0.f, cs = 0.f;
#pragma unroll
  for (int b = 0; b < 16; ++b) {
    rs += row_part[(size_t)b * N_ + i];
    cs += col_part[(size_t)b * N_ + i];
  }
  int cnt = hist[labels[i]];
  double term = (double)cnt * ((double)logf(rs) + (double)logf(cs));
  double sterm = (i < 256) ? (double)S_part[i] : 0.0;
#pragma unroll
  for (int m = 32; m; m >>= 1) {
    term += __shfl_xor(term, m);
    sterm += __shfl_xor(sterm, m);
  }
  __shared__ double tbuf[4], sb[4];
  int lane = tid & 63, w = tid >> 6;
  if (lane == 0) { tbuf[w] = term; sb[w] = sterm; }
  __syncthreads();
  if (tid == 0) {
    partials[blockIdx.x] = tbuf[0] + tbuf[1] + tbuf[2] + tbuf[3];
    partials[16 + blockIdx.x] = sb[0] + sb[1] + sb[2] + sb[3];
  }
}

__global__ void final_kernel(const double* __restrict__ partials, float* __restrict__ out) {
  double t = 0.0, s = 0.0;
#pragma unroll
  for (int i = 0; i < 16; ++i) {
    t += partials[i];
    s += partials[16 + i];
  }
  out[0] = (float)((t - 2.0 * s) / (2.0 * (double)N_));
}

extern "C" void kernel_launch(void* const* d_in, const int* in_sizes, int n_in,
                              void* d_out, int out_size, void* d_ws, size_t ws_size,
                              hipStream_t stream) {
  const float* img = (const float*)d_in[0];
  const float* txt = (const float*)d_in[1];
  const int* labels = (const int*)d_in[2];
  float* out = (float*)d_out;
  char* ws = (char*)d_ws;

  // workspace layout (bytes)
  __hip_bfloat16* img_nb = (__hip_bfloat16*)(ws);             //  6,291,456
  __hip_bfloat16* txt_nb = (__hip_bfloat16*)(ws + 6291456);   //  6,291,456
  float* row_part = (float*)(ws + 12582912);                  //    262,144 (16 x 4096)
  float* col_part = (float*)(ws + 12845056);                  //    262,144
  float* S_part = (float*)(ws + 13107200);                    //      1,024
  double* partials = (double*)(ws + 13108224);                //        256

  normalize_kernel<<<2 * N_, 192, 0, stream>>>(img, txt, img_nb, txt_nb);
  gemm_epi_kernel<<<dim3(16, 16), 512, 0, stream>>>(
      (const unsigned short*)img_nb, (const unsigned short*)txt_nb, labels,
      row_part, col_part, S_part);
  reduce_kernel<<<16, 256, 0, stream>>>(row_part, col_part, S_part, labels, partials);
  final_kernel<<<1, 1, 0, stream>>>(partials, out);
}

// Round 9
// 64.782 us; speedup vs baseline: 1.0799x; 1.0799x over previous
//
#include <hip/hip_runtime.h>
#include <hip/hip_bf16.h>

#define N_ 4096
#define D_ 768
#define NCLS 128
#define BM 128
#define BN 128
#define BKB 128   // K-bytes per step (fp8: 128 elems)
#define NSTEP 6   // D_/BKB

typedef float f32x4 __attribute__((ext_vector_type(4)));
typedef long lng2 __attribute__((ext_vector_type(2)));

// Normalize both embeddings to OCP fp8 e4m3 (blocks [0,N)->img, [N,2N)->txt).
// 192 threads x 4 elems; pack 4 fp8 into one int store (coalesced 768B/row).
__global__ __launch_bounds__(192) void normalize_kernel(
    const float* __restrict__ img, const float* __restrict__ txt,
    unsigned char* __restrict__ img_f8, unsigned char* __restrict__ txt_f8) {
  int b = blockIdx.x;
  const float* s;
  unsigned char* d;
  if (b < N_) {
    s = img + (size_t)b * D_;
    d = img_f8 + (size_t)b * D_;
  } else {
    s = txt + (size_t)(b - N_) * D_;
    d = txt_f8 + (size_t)(b - N_) * D_;
  }
  int tid = threadIdx.x;
  float4 v = ((const float4*)s)[tid];
  float ss = v.x * v.x + v.y * v.y + v.z * v.z + v.w * v.w;
#pragma unroll
  for (int m = 32; m; m >>= 1) ss += __shfl_xor(ss, m);
  __shared__ float wsum[3];
  int lane = tid & 63, w = tid >> 6;
  if (lane == 0) wsum[w] = ss;
  __syncthreads();
  float inv = 1.0f / fmaxf(sqrtf(wsum[0] + wsum[1] + wsum[2]), 1e-8f);
  int r = 0;
  r = __builtin_amdgcn_cvt_pk_fp8_f32(v.x * inv, v.y * inv, r, false);
  r = __builtin_amdgcn_cvt_pk_fp8_f32(v.z * inv, v.w * inv, r, true);
  ((int*)d)[tid] = r;
}

// 128x128-tile fp8 GEMM (r7 structure: 4 waves, VGPR staging + reg prefetch,
// conflict-free swizzle both sides), BK=128 fp8 elems -> 6 steps, 64 MFMA/step/wave.
// LDS row layout (128B): 16B slot s16 = 2g+p holds k-groups ks=2p,2p+1 of lane-group g;
// slot-XOR swizzle s16 ^= (row&7). Fragment read = ds_read_b128 covering 2 k-slices.
// mfma_f32_16x16x32_fp8_fp8 = bf16 rate, same 8-elem/lane k-grouping (k=(lane>>4)*8+j).
__global__ __launch_bounds__(256) void gemm_epi_kernel(
    const unsigned char* __restrict__ A, const unsigned char* __restrict__ B,
    const int* __restrict__ labels, float* __restrict__ row_part,
    float* __restrict__ col_part, float* __restrict__ S_part) {
  __shared__ __align__(16) unsigned char As[16384];  // 128 rows x 128B
  __shared__ __align__(16) unsigned char Bs[16384];
  __shared__ int labR[BM], labC[BN];
  __shared__ float rbuf[2][BM], cbuf[2][BN];
  __shared__ float sbuf[4];

  const int bx = blockIdx.x, by = blockIdx.y;
  const int tid = threadIdx.x;
  const int lane = tid & 63, wave = tid >> 6;
  const int wr = wave >> 1, wc = wave & 1;
  const int g = lane >> 4, fr = lane & 15;
  const int rowBase = by * BM, colBase = bx * BN;

  if (tid < BM) labR[tid] = labels[rowBase + tid];
  else labC[tid - BM] = labels[colBase + tid - BM];

  // staging: thread t covers 16B chunk gq=t&7 of rows rbase+32j (j=0..3)
  const int gq = tid & 7, rbase = tid >> 3;  // rbase 0..31
  const unsigned char* pa = A + (size_t)(rowBase + rbase) * D_ + gq * 16;
  const unsigned char* pb = B + (size_t)(colBase + rbase) * D_ + gq * 16;
  // global chunk gq = cells (g=2(gq&1), ks=gq>>1) and (g+1, ks): two b64 writes
  const int s16a = (gq & 1) * 4 + (gq >> 2);
  const int halfo = ((gq >> 1) & 1) * 8;
  const int rx = rbase & 7;
  const int w1 = rbase * 128 + ((s16a ^ rx) * 16) + halfo;        // + j*4096
  const int w2 = rbase * 128 + (((s16a + 2) ^ rx) * 16) + halfo;  // + j*4096

  f32x4 acc[4][4] = {};

  // prologue: step 0 into regs
  lng2 ra[4], rb[4];
#pragma unroll
  for (int j = 0; j < 4; ++j) {
    ra[j] = *(const lng2*)(pa + (size_t)(32 * j) * D_);
    rb[j] = *(const lng2*)(pb + (size_t)(32 * j) * D_);
  }

  for (int u = 0; u < NSTEP; ++u) {
    __syncthreads();  // all waves done reading LDS from previous step
#pragma unroll
    for (int j = 0; j < 4; ++j) {
      *(long*)&As[w1 + j * 4096] = ra[j].x;
      *(long*)&As[w2 + j * 4096] = ra[j].y;
      *(long*)&Bs[w1 + j * 4096] = rb[j].x;
      *(long*)&Bs[w2 + j * 4096] = rb[j].y;
    }
    if (u + 1 < NSTEP) {  // prefetch next step; lands during MFMA below
      const int k0 = (u + 1) * BKB;
#pragma unroll
      for (int j = 0; j < 4; ++j) {
        ra[j] = *(const lng2*)(pa + (size_t)(32 * j) * D_ + k0);
        rb[j] = *(const lng2*)(pb + (size_t)(32 * j) * D_ + k0);
      }
    }
    __syncthreads();  // tile u resident
#pragma unroll
    for (int p = 0; p < 2; ++p) {  // k-slice pairs (ks=2p, 2p+1)
      const int sw = ((g << 1) | p) ^ (fr & 7);  // phys 16B slot
      lng2 bq[4];
#pragma unroll
      for (int n = 0; n < 4; ++n)
        bq[n] = *(const lng2*)&Bs[(wc * 64 + n * 16 + fr) * 128 + sw * 16];
#pragma unroll
      for (int m = 0; m < 4; ++m) {
        lng2 aq = *(const lng2*)&As[(wr * 64 + m * 16 + fr) * 128 + sw * 16];
#pragma unroll
        for (int n = 0; n < 4; ++n) {
          acc[m][n] = __builtin_amdgcn_mfma_f32_16x16x32_fp8_fp8(aq.x, bq[n].x, acc[m][n], 0, 0, 0);
          acc[m][n] = __builtin_amdgcn_mfma_f32_16x16x32_fp8_fp8(aq.y, bq[n].y, acc[m][n], 0, 0, 0);
        }
      }
    }
  }
  __syncthreads();

  const float scale = 14.285714285714286f;  // 1/0.07
  float sPart = 0.f;
  float colAcc[4] = {0.f, 0.f, 0.f, 0.f};
#pragma unroll
  for (int m = 0; m < 4; ++m) {
    float ra2[4] = {0.f, 0.f, 0.f, 0.f};
#pragma unroll
    for (int n = 0; n < 4; ++n) {
      int col = wc * 64 + n * 16 + fr;
      int lc = labC[col];
#pragma unroll
      for (int r = 0; r < 4; ++r) {
        float v = acc[m][n][r] * scale;
        float e = __expf(v);
        ra2[r] += e;
        colAcc[n] += e;
        int row = wr * 64 + m * 16 + g * 4 + r;
        if (labR[row] == lc) sPart += v;
      }
    }
#pragma unroll
    for (int r = 0; r < 4; ++r) {
      float x = ra2[r];
      x += __shfl_xor(x, 1);
      x += __shfl_xor(x, 2);
      x += __shfl_xor(x, 4);
      x += __shfl_xor(x, 8);
      if (fr == 0) rbuf[wc][wr * 64 + m * 16 + g * 4 + r] = x;
    }
  }
#pragma unroll
  for (int n = 0; n < 4; ++n) {
    float x = colAcc[n];
    x += __shfl_xor(x, 16);
    x += __shfl_xor(x, 32);
    if (g == 0) cbuf[wr][wc * 64 + n * 16 + fr] = x;
  }
  float s = sPart;
#pragma unroll
  for (int m = 32; m; m >>= 1) s += __shfl_xor(s, m);
  if (lane == 0) sbuf[wave] = s;
  __syncthreads();
  if (tid < BM)
    row_part[(size_t)bx * N_ + rowBase + tid] = rbuf[0][tid] + rbuf[1][tid];
  else
    col_part[(size_t)by * N_ + colBase + (tid - BM)] = cbuf[0][tid - BM] + cbuf[1][tid - BM];
  if (tid == 0) S_part[by * 32 + bx] = sbuf[0] + sbuf[1] + sbuf[2] + sbuf[3];
}

// Per-block local histogram; partials out (no atomics, no memset needed)
__global__ __launch_bounds__(256) void reduce_kernel(
    const float* __restrict__ row_part, const float* __restrict__ col_part,
    const float* __restrict__ S_part, const int* __restrict__ labels,
    double* __restrict__ partials) {
  __shared__ int hist[NCLS];
  int tid = threadIdx.x;
  if (tid < NCLS) hist[tid] = 0;
  __syncthreads();
  for (int j = tid; j < N_; j += 256) atomicAdd(&hist[labels[j]], 1);
  __syncthreads();

  int i = blockIdx.x * 256 + tid;  // 0..4095
  float rs = 0.f, cs = 0.f;
#pragma unroll
  for (int b = 0; b < 32; ++b) {
    rs += row_part[(size_t)b * N_ + i];
    cs += col_part[(size_t)b * N_ + i];
  }
  int cnt = hist[labels[i]];
  double term = (double)cnt * ((double)logf(rs) + (double)logf(cs));
  double sterm = (i < 1024) ? (double)S_part[i] : 0.0;
#pragma unroll
  for (int m = 32; m; m >>= 1) {
    term += __shfl_xor(term, m);
    sterm += __shfl_xor(sterm, m);
  }
  __shared__ double tbuf[4], sb[4];
  int lane = tid & 63, w = tid >> 6;
  if (lane == 0) { tbuf[w] = term; sb[w] = sterm; }
  __syncthreads();
  if (tid == 0) {
    partials[blockIdx.x] = tbuf[0] + tbuf[1] + tbuf[2] + tbuf[3];
    partials[16 + blockIdx.x] = sb[0] + sb[1] + sb[2] + sb[3];
  }
}

__global__ void final_kernel(const double* __restrict__ partials, float* __restrict__ out) {
  double t = 0.0, s = 0.0;
#pragma unroll
  for (int i = 0; i < 16; ++i) {
    t += partials[i];
    s += partials[16 + i];
  }
  out[0] = (float)((t - 2.0 * s) / (2.0 * (double)N_));
}

extern "C" void kernel_launch(void* const* d_in, const int* in_sizes, int n_in,
                              void* d_out, int out_size, void* d_ws, size_t ws_size,
                              hipStream_t stream) {
  const float* img = (const float*)d_in[0];
  const float* txt = (const float*)d_in[1];
  const int* labels = (const int*)d_in[2];
  float* out = (float*)d_out;
  char* ws = (char*)d_ws;

  // workspace layout (bytes)
  unsigned char* img_f8 = (unsigned char*)(ws);            //  3,145,728
  unsigned char* txt_f8 = (unsigned char*)(ws + 3145728);  //  3,145,728
  float* row_part = (float*)(ws + 6291456);                //    524,288 (32 x 4096)
  float* col_part = (float*)(ws + 6815744);                //    524,288
  float* S_part = (float*)(ws + 7340032);                  //      4,096
  double* partials = (double*)(ws + 7344128);              //        256

  normalize_kernel<<<2 * N_, 192, 0, stream>>>(img, txt, img_f8, txt_f8);
  gemm_epi_kernel<<<dim3(32, 32), 256, 0, stream>>>(
      img_f8, txt_f8, labels, row_part, col_part, S_part);
  reduce_kernel<<<16, 256, 0, stream>>>(row_part, col_part, S_part, labels, partials);
  final_kernel<<<1, 1, 0, stream>>>(partials, out);
}